// Round 1
// baseline (154.274 us; speedup 1.0000x reference)
//
#include <hip/hip_runtime.h>
#include <hip/hip_bf16.h>

#define IN_F 4096
#define OUT_F 11008
#define TOKENS 32
#define RANK 16
#define KSPLIT 8
#define KSLICE (IN_F / KSPLIT)     // 512
#define XPAD 520                   // u16 per LDS x-row (512 data + 8 pad) -> 1040B rows, 16B aligned
#define OUT_ELEMS (TOKENS * OUT_F) // 352256
#define NBLK (OUT_F / 64)          // 172

typedef unsigned short u16;
typedef __attribute__((ext_vector_type(8))) short bf16x8;
typedef __attribute__((ext_vector_type(4))) float f32x4;
typedef __attribute__((ext_vector_type(4))) int i32x4;

__device__ const float NF4_d[16] = {
    -1.0f, -0.6961928009986877f, -0.5250730514526367f, -0.39491748809814453f,
    -0.28444138169288635f, -0.18477343022823334f, -0.09105003625154495f, 0.0f,
    0.07958029955625534f, 0.16093020141124725f, 0.24611230194568634f,
    0.33791524171829224f, 0.44070982933044434f, 0.5626170039176941f,
    0.7229568362236023f, 1.0f};

static __device__ __forceinline__ unsigned pk2(float a, float b) {
    __hip_bfloat162 h = __float22bfloat162_rn(make_float2(a, b));
    unsigned u;
    __builtin_memcpy(&u, &h, 4);
    return u;
}

// prep: blocks 0..511 xa[t][r]; 512..527 x fp32->bf16 into ws; 528..591 zero out (fallback mode only)
__global__ void prep_kernel(const float* __restrict__ x, const float* __restrict__ A,
                            float* __restrict__ xa, u16* __restrict__ xb,
                            float* __restrict__ out) {
    if (blockIdx.x >= 528) {  // zero out[] (atomic-fallback mode only)
        int i = (blockIdx.x - 528) * 256 + threadIdx.x;  // 0..16383
        float4 z = make_float4(0.f, 0.f, 0.f, 0.f);
        for (int j = i; j < OUT_ELEMS / 4; j += 16384) ((float4*)out)[j] = z;
        return;
    }
    if (blockIdx.x >= 512) {  // convert x -> bf16 once (32x4096 u16 = 256 KB)
        int i = (blockIdx.x - 512) * 256 + threadIdx.x;  // 0..4095
#pragma unroll
        for (int j = 0; j < 8; ++j) {
            int idx = j * 4096 + i;  // float4 index, 32768 total
            float4 v = ((const float4*)x)[idx];
            uint2 d;
            d.x = pk2(v.x, v.y);
            d.y = pk2(v.z, v.w);
            ((uint2*)xb)[idx] = d;
        }
        return;
    }
    __shared__ float red[256];
    int b = blockIdx.x;  // 0..511
    int t = b >> 4, r = b & 15;
    const float4* xr = (const float4*)(x + t * IN_F);
    const float4* ar = (const float4*)(A + r * IN_F);
    float s = 0.f;
    for (int c = 0; c < 4; ++c) {
        int j = c * 256 + threadIdx.x;
        float4 xv = xr[j], av = ar[j];
        s += xv.x * av.x + xv.y * av.y + xv.z * av.z + xv.w * av.w;
    }
    red[threadIdx.x] = s;
    __syncthreads();
    for (int st = 128; st > 0; st >>= 1) {
        if (threadIdx.x < st) red[threadIdx.x] += red[threadIdx.x + st];
        __syncthreads();
    }
    if (threadIdx.x == 0) xa[b] = red[0];
}

// MODE 0: write split-K partials to ws (no atomics). MODE 1: legacy atomicAdd + fused lora.
template <int MODE>
__global__ __launch_bounds__(256, 4) void qlora_fused(
    const int* __restrict__ packed, const float* __restrict__ scales,
    const u16* __restrict__ xb, const float* __restrict__ xa,
    const float* __restrict__ B, float* __restrict__ outp) {
    __shared__ u16 xs[32 * XPAD];
    __shared__ unsigned tbl[256];  // byte -> final packed bf16 pair {lo16=hi-nib code, hi16=lo-nib code}
    __shared__ float xal[512];
    const int tid = threadIdx.x;
    const int kbase = blockIdx.y * KSLICE;
    const int obase = blockIdx.x * 64;

    const int lane = tid & 63;
    const int wv = tid >> 6;
    const int n = lane & 15;  // output col within wave tile
    const int q = lane >> 4;  // k-subblock
    const int o = obase + wv * 16 + n;

    // deep packed prefetch FIRST (nontemporal: 90 MB single-use stream)
    const i32x4* ppq = (const i32x4*)(packed + o * 2048 + (kbase >> 1)) + q;
    i32x4 P[4];
    P[0] = __builtin_nontemporal_load(ppq);
    P[1] = __builtin_nontemporal_load(ppq + 4);
    P[2] = __builtin_nontemporal_load(ppq + 8);
    P[3] = __builtin_nontemporal_load(ppq + 12);

    // per-lane group scales (8 floats, 32B contiguous)
    const float4* sp = (const float4*)(scales + o * 64 + (kbase >> 6));
    float4 sA = sp[0], sB = sp[1];

    // table entry IS the B-fragment dword: element0 (low16) = hi-nibble code (k even first)
    tbl[tid] = pk2(NF4_d[tid >> 4], NF4_d[tid & 15]);

    if (MODE == 1 && blockIdx.y == 0) {  // stage xa for fused lora epilogue (fallback)
        xal[tid] = xa[tid];
        xal[tid + 256] = xa[tid + 256];
    }

    // stage x slice: pre-converted bf16, direct global->LDS, one row per call
    {
        const u16* src = xb + kbase + lane * 8;
#pragma unroll
        for (int rr = 0; rr < 8; ++rr) {
            int row = rr * 4 + wv;  // wave-uniform
            __builtin_amdgcn_global_load_lds(
                (const __attribute__((address_space(1))) unsigned int*)(src + row * IN_F),
                (__attribute__((address_space(3))) unsigned int*)(xs + row * XPAD),
                16, 0, 0);
        }
    }
    __syncthreads();

    f32x4 acc0 = {0.f, 0.f, 0.f, 0.f};
    f32x4 acc1 = {0.f, 0.f, 0.f, 0.f};
    const u16* xr0 = xs + n * XPAD + q * 8;
    const u16* xr1 = xs + (n + 16) * XPAD + q * 8;
    const float scr[8] = {sA.x, sA.y, sA.z, sA.w, sB.x, sB.y, sB.z, sB.w};

#pragma unroll
    for (int g = 0; g < 8; ++g) {  // one 64-wide scale group = 2 MFMA steps
        f32x4 p0 = {0.f, 0.f, 0.f, 0.f};
        f32x4 p1 = {0.f, 0.f, 0.f, 0.f};
#pragma unroll
        for (int h = 0; h < 2; ++h) {
            const int s = g * 2 + h;
            i32x4 cur = P[s & 3];
            if (s + 4 < 16) P[s & 3] = __builtin_nontemporal_load(ppq + (s + 4) * 4);
            // packed ints are 0..255 by construction (randint(0,256)) -> direct index
            uint4 bu;
            bu.x = tbl[cur[0]];
            bu.y = tbl[cur[1]];
            bu.z = tbl[cur[2]];
            bu.w = tbl[cur[3]];
            bf16x8 bfrag;
            __builtin_memcpy(&bfrag, &bu, 16);
            bf16x8 a0 = *(const bf16x8*)(xr0 + s * 32);
            bf16x8 a1 = *(const bf16x8*)(xr1 + s * 32);
            p0 = __builtin_amdgcn_mfma_f32_16x16x32_bf16(a0, bfrag, p0, 0, 0, 0);
            p1 = __builtin_amdgcn_mfma_f32_16x16x32_bf16(a1, bfrag, p1, 0, 0, 0);
        }
        const float sc = scr[g];
#pragma unroll
        for (int r = 0; r < 4; ++r) {
            acc0[r] = fmaf(sc, p0[r], acc0[r]);
            acc1[r] = fmaf(sc, p1[r], acc1[r]);
        }
    }

    if (MODE == 0) {
        // partials: per-block contiguous 2048 floats, lane-contiguous 32B stores
        float* wp = outp + (blockIdx.y * NBLK + blockIdx.x) * 2048 + tid * 8;
        float4 v0 = make_float4(acc0[0], acc0[1], acc0[2], acc0[3]);
        float4 v1 = make_float4(acc1[0], acc1[1], acc1[2], acc1[3]);
        *(float4*)wp = v0;
        *(float4*)(wp + 4) = v1;
    } else {
        // legacy: fused lora (y==0) + atomicAdd epilogue
        float lora[8] = {0.f, 0.f, 0.f, 0.f, 0.f, 0.f, 0.f, 0.f};
        if (blockIdx.y == 0) {
            const float4* br = (const float4*)(B + o * RANK);
            float4 b0 = br[0], b1 = br[1], b2 = br[2], b3 = br[3];
#pragma unroll
            for (int r = 0; r < 4; ++r) {
                const float* x0 = xal + (q * 4 + r) * RANK;
                const float* x1 = xal + (q * 4 + r + 16) * RANK;
                float s0 = b0.x * x0[0] + b0.y * x0[1] + b0.z * x0[2] + b0.w * x0[3] +
                           b1.x * x0[4] + b1.y * x0[5] + b1.z * x0[6] + b1.w * x0[7] +
                           b2.x * x0[8] + b2.y * x0[9] + b2.z * x0[10] + b2.w * x0[11] +
                           b3.x * x0[12] + b3.y * x0[13] + b3.z * x0[14] + b3.w * x0[15];
                float s1 = b0.x * x1[0] + b0.y * x1[1] + b0.z * x1[2] + b0.w * x1[3] +
                           b1.x * x1[4] + b1.y * x1[5] + b1.z * x1[6] + b1.w * x1[7] +
                           b2.x * x1[8] + b2.y * x1[9] + b2.z * x1[10] + b2.w * x1[11] +
                           b3.x * x1[12] + b3.y * x1[13] + b3.z * x1[14] + b3.w * x1[15];
                lora[r] = s0;
                lora[r + 4] = s1;
            }
        }
#pragma unroll
        for (int r = 0; r < 4; ++r) {
            int t = q * 4 + r;
            atomicAdd(outp + t * OUT_F + o, acc0[r] + lora[r]);
            atomicAdd(outp + (t + 16) * OUT_F + o, acc1[r] + lora[r + 4]);
        }
    }
}

// sum 8 split-K partials + lora epilogue, plain stores (no atomics anywhere)
__global__ __launch_bounds__(256) void reduce_out(
    const float* __restrict__ part, const float* __restrict__ xa,
    const float* __restrict__ B, float* __restrict__ out) {
    __shared__ float xal[512];
    const int tid = threadIdx.x;
    const int bx = blockIdx.x;  // 0..171
    xal[tid] = xa[tid];
    xal[tid + 256] = xa[tid + 256];
    __syncthreads();

    const float4* p = (const float4*)part + bx * 512 + tid * 2;
    float4 s0 = p[0], s1 = p[1];
#pragma unroll
    for (int s = 1; s < 8; ++s) {
        float4 a = p[s * (NBLK * 512)];
        float4 b = p[s * (NBLK * 512) + 1];
        s0.x += a.x; s0.y += a.y; s0.z += a.z; s0.w += a.w;
        s1.x += b.x; s1.y += b.y; s1.z += b.z; s1.w += b.w;
    }

    const int lane = tid & 63, wv = tid >> 6, n = lane & 15, q = lane >> 4;
    const int o = bx * 64 + wv * 16 + n;
    const float4* br = (const float4*)(B + o * RANK);
    float4 b0 = br[0], b1 = br[1], b2 = br[2], b3 = br[3];
    float res[8] = {s0.x, s0.y, s0.z, s0.w, s1.x, s1.y, s1.z, s1.w};
#pragma unroll
    for (int r = 0; r < 4; ++r) {
        int t0 = q * 4 + r;
        const float* x0 = xal + t0 * RANK;
        const float* x1 = xal + (t0 + 16) * RANK;
        float l0 = b0.x * x0[0] + b0.y * x0[1] + b0.z * x0[2] + b0.w * x0[3] +
                   b1.x * x0[4] + b1.y * x0[5] + b1.z * x0[6] + b1.w * x0[7] +
                   b2.x * x0[8] + b2.y * x0[9] + b2.z * x0[10] + b2.w * x0[11] +
                   b3.x * x0[12] + b3.y * x0[13] + b3.z * x0[14] + b3.w * x0[15];
        float l1 = b0.x * x1[0] + b0.y * x1[1] + b0.z * x1[2] + b0.w * x1[3] +
                   b1.x * x1[4] + b1.y * x1[5] + b1.z * x1[6] + b1.w * x1[7] +
                   b2.x * x1[8] + b2.y * x1[9] + b2.z * x1[10] + b2.w * x1[11] +
                   b3.x * x1[12] + b3.y * x1[13] + b3.z * x1[14] + b3.w * x1[15];
        out[t0 * OUT_F + o] = res[r] + l0;
        out[(t0 + 16) * OUT_F + o] = res[r + 4] + l1;
    }
}

extern "C" void kernel_launch(void* const* d_in, const int* in_sizes, int n_in,
                              void* d_out, int out_size, void* d_ws, size_t ws_size,
                              hipStream_t stream) {
    const float* x = (const float*)d_in[0];
    const int* packed = (const int*)d_in[1];
    const float* scales = (const float*)d_in[2];
    const float* lora_A = (const float*)d_in[3];
    const float* lora_B = (const float*)d_in[4];
    float* out = (float*)d_out;

    float* xa = (float*)d_ws;                                      // 2 KB
    u16* xb = (u16*)((char*)d_ws + 2048);                          // 256 KB bf16 x
    float* part = (float*)((char*)d_ws + 2048 + TOKENS * IN_F * 2);// 11.0 MB partials
    size_t need = 2048 + (size_t)TOKENS * IN_F * 2 +
                  (size_t)KSPLIT * NBLK * 2048 * sizeof(float);

    if (ws_size >= need) {
        prep_kernel<<<528, 256, 0, stream>>>(x, lora_A, xa, xb, out);
        qlora_fused<0><<<dim3(NBLK, KSPLIT), 256, 0, stream>>>(packed, scales, xb, xa,
                                                               lora_B, part);
        reduce_out<<<NBLK, 256, 0, stream>>>(part, xa, lora_B, out);
    } else {  // fallback: legacy atomic path (needs only xa+xb in ws)
        prep_kernel<<<592, 256, 0, stream>>>(x, lora_A, xa, xb, out);
        qlora_fused<1><<<dim3(NBLK, KSPLIT), 256, 0, stream>>>(packed, scales, xb, xa,
                                                               lora_B, out);
    }
}